// Round 3
// baseline (358.956 us; speedup 1.0000x reference)
//
#include <hip/hip_runtime.h>

// XY model log-density: out[b] = sum_s [cos(th[up(s)]-th[s]) + cos(th[right(s)]-th[s])]
// 64x64 periodic lattice, 16384 samples. up=(y+1)%64, right=(x+1)%64.
//
// Register-only streaming design: each lane owns 4 consecutive columns (float4) of one
// sample and walks y=0..63. Every input byte is loaded exactly once chip-wide; vertical
// neighbor pairs use the registered previous row, horizontal pairs are in-register plus
// one cross-lane __shfl for the quad boundary. No LDS, no barriers, no vmcnt(0) drains.
// 16 lanes/sample, 4 samples/wave, 4 waves/block -> 16 samples/block, 1024 blocks.

#define LAT_L    64
#define NSITE    4096
#define BLOCK    256
#define NSAMPLE  16384
#define SPB      16                  // samples per block (4 per wave)
#define NBLK     (NSAMPLE / SPB)     // 1024

__device__ __forceinline__ float vert_sum(const float4 a, const float4 b) {
    // sum_j cos(b[j] - a[j])
    return __cosf(b.x - a.x) + __cosf(b.y - a.y) +
           __cosf(b.z - a.z) + __cosf(b.w - a.w);
}

__device__ __forceinline__ float horiz_sum(const float4 v, const int nbr) {
    // 3 in-quad pairs + boundary pair against next lane's first column
    const float n0 = __shfl(v.x, nbr, 64);
    return __cosf(v.y - v.x) + __cosf(v.z - v.y) +
           __cosf(v.w - v.z) + __cosf(n0 - v.w);
}

__global__ __launch_bounds__(BLOCK)
void xy_logdensity_kernel(const float* __restrict__ state, float* __restrict__ out) {
    const int t = threadIdx.x;
    const int l = t & 63;            // lane in wave
    const int w = t >> 6;            // wave in block
    const int g = l >> 4;            // sample sub-index within wave (0..3)
    const int q = l & 15;            // column quad (covers x = 4q..4q+3)

    const long sample = (long)blockIdx.x * SPB + w * 4 + g;
    const float4* __restrict__ row = (const float4*)(state + sample * NSITE) + q;
    // neighbor lane for the horizontal boundary: next quad in the same 16-lane group,
    // q=15 wraps to q=0 (x=63 -> x=0, the periodic wrap)
    const int nbr = (l & 48) | ((l + 1) & 15);

    // rows in float4 units: row y is at offset y*16
    float4 first = row[0];
    float4 cur   = first;
    float4 nxt   = row[16];

    float sum = horiz_sum(cur, nbr);

#pragma unroll 4
    for (int y = 1; y < LAT_L - 1; ++y) {
        const float4 pf = row[(y + 1) * 16];   // prefetch row y+1 (2 loads in flight)
        sum += vert_sum(cur, nxt);             // pair (y-1, y)
        sum += horiz_sum(nxt, nbr);            // row y
        cur = nxt;
        nxt = pf;
    }
    sum += vert_sum(cur, nxt);                 // pair (62, 63)
    sum += horiz_sum(nxt, nbr);                // row 63
    sum += vert_sum(nxt, first);               // wrap pair (63, 0)

    // reduce across the 16 lanes of this sample
#pragma unroll
    for (int off = 8; off > 0; off >>= 1)
        sum += __shfl_xor(sum, off, 16);

    if (q == 0)
        out[sample] = sum;   // BETA = 1.0
}

extern "C" void kernel_launch(void* const* d_in, const int* in_sizes, int n_in,
                              void* d_out, int out_size, void* d_ws, size_t ws_size,
                              hipStream_t stream) {
    const float* state = (const float*)d_in[0];
    // d_in[1] (int64 shift table) is the deterministic 64x64 periodic roll;
    // neighbor indices are computed structurally instead of gathered.
    float* out = (float*)d_out;

    xy_logdensity_kernel<<<NBLK, BLOCK, 0, stream>>>(state, out);
}

// Round 4
// 352.504 us; speedup vs baseline: 1.0183x; 1.0183x over previous
//
#include <hip/hip_runtime.h>

// XY model log-density: out[b] = sum_s [cos(th[up(s)]-th[s]) + cos(th[right(s)]-th[s])]
// 64x64 periodic lattice, 16384 samples. up=(y+1)%64, right=(x+1)%64.
//
// Register-only streaming, max-occupancy variant: each 16-lane group owns a 32-row
// y-slab of one sample (lane = 4-column quad). Two slabs per sample live in one wave
// (lanes 0-15/16-31 = sample A slabs, 32-47/48-63 = sample B slabs), so the +1 halo row
// each slab needs is read by the sibling group as a regular row -> L1 hit (+3% nominal).
// Horizontal pairs: 3 in-register + 1 cross-lane __shfl. Vertical pairs: registered
// previous row. No LDS, no barriers. 2048 blocks x 4 waves = 8192 waves = 32 waves/CU
// (hardware max); __launch_bounds__(256,8) caps VGPRs at 64 to make that feasible.

#define LAT_L    64
#define NSITE    4096
#define BLOCK    256
#define NSAMPLE  16384
#define SPB      8                   // samples per block (2 per wave)
#define NBLK     (NSAMPLE / SPB)     // 2048

__device__ __forceinline__ float vert_sum(const float4 a, const float4 b) {
    return __cosf(b.x - a.x) + __cosf(b.y - a.y) +
           __cosf(b.z - a.z) + __cosf(b.w - a.w);
}

__device__ __forceinline__ float horiz_sum(const float4 v, const int nbr) {
    const float n0 = __shfl(v.x, nbr, 64);   // next quad's first column (x-wrap at q=15)
    return __cosf(v.y - v.x) + __cosf(v.z - v.y) +
           __cosf(v.w - v.z) + __cosf(n0 - v.w);
}

__global__ __launch_bounds__(BLOCK, 8)   // 8 waves/SIMD = 32 waves/CU; forces VGPR<=64
void xy_logdensity_kernel(const float* __restrict__ state, float* __restrict__ out) {
    const int t    = threadIdx.x;
    const int l    = t & 63;
    const int w    = t >> 6;
    const int half = l >> 5;          // which sample within the wave (0/1)
    const int grp  = (l >> 4) & 1;    // which 32-row slab (0/1)
    const int q    = l & 15;          // column quad: covers x = 4q..4q+3

    const long sample = (long)blockIdx.x * SPB + w * 2 + half;
    const float4* __restrict__ row = (const float4*)(state + sample * NSITE);
    const int y0 = grp << 5;          // slab origin: 0 or 32
    const float4* __restrict__ rp = row + y0 * 16 + q;   // rows in float4: row y at y*16

    // horizontal boundary neighbor: next quad in this 16-lane group, q=15 wraps to q=0
    const int nbr = (l & 48) | ((l + 1) & 15);

    // software pipeline, prefetch depth 1
    float4 cur = rp[0];
    float4 nxt = rp[16];
    float s = horiz_sum(cur, nbr);

#pragma unroll 4
    for (int r = 1; r < 31; ++r) {
        const float4 pf = rp[(r + 1) * 16];
        s += vert_sum(cur, nxt);      // vertical pair (y0+r-1, y0+r)
        s += horiz_sum(nxt, nbr);     // row y0+r
        cur = nxt;
        nxt = pf;
    }
    s += vert_sum(cur, nxt);          // pair (y0+30, y0+31)
    s += horiz_sum(nxt, nbr);         // row y0+31
    const float4 halo = row[(y0 ^ 32) * 16 + q];   // row (y0+32) mod 64
    s += vert_sum(nxt, halo);         // boundary pair (y0+31, y0+32)

    // reduce over the 32 lanes (two slabs) of this sample
#pragma unroll
    for (int off = 16; off > 0; off >>= 1)
        s += __shfl_xor(s, off, 32);

    if ((l & 31) == 0)
        out[sample] = s;              // BETA = 1.0
}

extern "C" void kernel_launch(void* const* d_in, const int* in_sizes, int n_in,
                              void* d_out, int out_size, void* d_ws, size_t ws_size,
                              hipStream_t stream) {
    const float* state = (const float*)d_in[0];
    // d_in[1] (int64 shift table) is the deterministic 64x64 periodic roll;
    // neighbor indices are computed structurally instead of gathered.
    float* out = (float*)d_out;

    xy_logdensity_kernel<<<NBLK, BLOCK, 0, stream>>>(state, out);
}